// Round 1
// baseline (179.509 us; speedup 1.0000x reference)
//
#include <hip/hip_runtime.h>
#include <hip/hip_bf16.h>
#include <math.h>

// Attention_1322849927553: B=8, S=1024, D=512, H=8, hd=64, additive pos bias.
// Flash-style fused attention, bf16 MFMA (16x16x32), fp32 softmax/accum.

typedef __attribute__((ext_vector_type(8))) short short8;
typedef __attribute__((ext_vector_type(4))) float f32x4;
typedef __attribute__((ext_vector_type(4))) unsigned short u16x4;

#define SEQ   1024
#define DM    512
#define HD    64
#define SCALE 0.125f

__device__ __forceinline__ unsigned short f2bf(float f) {
    unsigned u = __float_as_uint(f);
    u += 0x7fffu + ((u >> 16) & 1u);   // round-to-nearest-even
    return (unsigned short)(u >> 16);
}

__device__ __forceinline__ u16x4 pack4(float a, float b, float c, float d) {
    u16x4 r; r[0] = f2bf(a); r[1] = f2bf(b); r[2] = f2bf(c); r[3] = f2bf(d);
    return r;
}

__global__ __launch_bounds__(256, 3)
void attn_fwd(const float* __restrict__ q, const float* __restrict__ k,
              const float* __restrict__ v, const float* __restrict__ bias,
              float* __restrict__ out)
{
    // rows padded 64 -> 72 elems (144 B) to spread LDS banks
    __shared__ short Klds[64][72];   // K tile, row-major [krow][d]
    __shared__ short Vt[64][72];     // V tile, transposed [d][krow]
    __shared__ short Plds[4][16][72];// per-wave P [qrow][kcol]

    const int t    = threadIdx.x;
    const int wid  = t >> 6;
    const int lane = t & 63;
    const int qr   = lane & 15;   // q-row (local) for S^T layout
    const int g    = lane >> 4;   // lane group 0..3

    int idx = blockIdx.x;
    const int b = idx & 7;  idx >>= 3;
    const int h = idx & 7;
    const int qtile = idx >> 3;
    const int qbase = qtile * 64 + wid * 16;

    // ---- Q fragments (B operand of swapped QK^T), scaled by SCALE ----
    const float* qp = q + ((b * SEQ + qbase + qr) * DM + h * HD);
    short8 qf[2];
#pragma unroll
    for (int c = 0; c < 2; ++c) {
        float4 x0 = *reinterpret_cast<const float4*>(qp + g * 8 + 32 * c);
        float4 x1 = *reinterpret_cast<const float4*>(qp + g * 8 + 32 * c + 4);
        short8 f;
        f[0] = (short)f2bf(x0.x * SCALE); f[1] = (short)f2bf(x0.y * SCALE);
        f[2] = (short)f2bf(x0.z * SCALE); f[3] = (short)f2bf(x0.w * SCALE);
        f[4] = (short)f2bf(x1.x * SCALE); f[5] = (short)f2bf(x1.y * SCALE);
        f[6] = (short)f2bf(x1.z * SCALE); f[7] = (short)f2bf(x1.w * SCALE);
        qf[c] = f;
    }

    f32x4 o[4];
#pragma unroll
    for (int nt = 0; nt < 4; ++nt) o[nt] = (f32x4){0.f, 0.f, 0.f, 0.f};
    float mrun = -INFINITY, lrun = 0.f;

    const int jrow = t & 63;   // staging row (K) / dest row d (Vt)
    const int cc   = t >> 6;   // staging 16-col chunk

    for (int kt = 0; kt < 16; ++kt) {
        const int kbase = kt * 64;

        // ---- stage K tile (row-major), 64B per thread, vectorized ----
        {
            const float4* kp4 = reinterpret_cast<const float4*>(
                k + ((b * SEQ + kbase + jrow) * DM + h * HD + cc * 16));
            float4 a0 = kp4[0], a1 = kp4[1], a2 = kp4[2], a3 = kp4[3];
            u16x4* dst = reinterpret_cast<u16x4*>(&Klds[jrow][cc * 16]);
            dst[0] = pack4(a0.x, a0.y, a0.z, a0.w);
            dst[1] = pack4(a1.x, a1.y, a1.z, a1.w);
            dst[2] = pack4(a2.x, a2.y, a2.z, a2.w);
            dst[3] = pack4(a3.x, a3.y, a3.z, a3.w);
        }
        // ---- stage V^T: coalesced column reads, vector LDS writes ----
        {
            const float* vp = v + ((b * SEQ + kbase + cc * 16) * DM + h * HD + jrow);
            float vv[16];
#pragma unroll
            for (int jj = 0; jj < 16; ++jj) vv[jj] = vp[jj * DM];
            u16x4* dst = reinterpret_cast<u16x4*>(&Vt[jrow][cc * 16]);
            dst[0] = pack4(vv[0],  vv[1],  vv[2],  vv[3]);
            dst[1] = pack4(vv[4],  vv[5],  vv[6],  vv[7]);
            dst[2] = pack4(vv[8],  vv[9],  vv[10], vv[11]);
            dst[3] = pack4(vv[12], vv[13], vv[14], vv[15]);
        }
        __syncthreads();

        // ---- bias prefetch (overlaps with MFMAs below) ----
        const float* bp = bias + ((h * SEQ + qbase + qr) * SEQ + kbase + g * 4);
        float4 bv0 = *reinterpret_cast<const float4*>(bp);
        float4 bv1 = *reinterpret_cast<const float4*>(bp + 16);
        float4 bv2 = *reinterpret_cast<const float4*>(bp + 32);
        float4 bv3 = *reinterpret_cast<const float4*>(bp + 48);

        // ---- S^T tile: mfma(K, Q) -> lane holds S[q=qr][k=16*mt+4*g+r] ----
        f32x4 acc[4];
#pragma unroll
        for (int mt = 0; mt < 4; ++mt) {
            f32x4 a = (f32x4){0.f, 0.f, 0.f, 0.f};
#pragma unroll
            for (int c = 0; c < 2; ++c) {
                short8 kf = *reinterpret_cast<const short8*>(
                    &Klds[qr + 16 * mt][g * 8 + 32 * c]);
                a = __builtin_amdgcn_mfma_f32_16x16x32_bf16(kf, qf[c], a, 0, 0, 0);
            }
            acc[mt] = a;
        }
        acc[0][0] += bv0.x; acc[0][1] += bv0.y; acc[0][2] += bv0.z; acc[0][3] += bv0.w;
        acc[1][0] += bv1.x; acc[1][1] += bv1.y; acc[1][2] += bv1.z; acc[1][3] += bv1.w;
        acc[2][0] += bv2.x; acc[2][1] += bv2.y; acc[2][2] += bv2.z; acc[2][3] += bv2.w;
        acc[3][0] += bv3.x; acc[3][1] += bv3.y; acc[3][2] += bv3.z; acc[3][3] += bv3.w;

        // ---- online softmax (row q=qr spread over lanes {qr,qr+16,qr+32,qr+48}) ----
        float tmax = acc[0][0];
#pragma unroll
        for (int mt = 0; mt < 4; ++mt)
#pragma unroll
            for (int r = 0; r < 4; ++r) tmax = fmaxf(tmax, acc[mt][r]);
        tmax = fmaxf(tmax, __shfl_xor(tmax, 16));
        tmax = fmaxf(tmax, __shfl_xor(tmax, 32));
        const float mnew = fmaxf(mrun, tmax);

        float p[4][4];
        float ssum = 0.f;
#pragma unroll
        for (int mt = 0; mt < 4; ++mt)
#pragma unroll
            for (int r = 0; r < 4; ++r) {
                float e = __expf(acc[mt][r] - mnew);
                p[mt][r] = e;
                ssum += e;
            }
        ssum += __shfl_xor(ssum, 16);
        ssum += __shfl_xor(ssum, 32);
        const float sc = __expf(mrun - mnew);   // first iter: exp(-inf)=0
        lrun = lrun * sc + ssum;
        mrun = mnew;

        // ---- write P (bf16) to per-wave LDS ----
#pragma unroll
        for (int mt = 0; mt < 4; ++mt) {
            *reinterpret_cast<u16x4*>(&Plds[wid][qr][16 * mt + g * 4]) =
                pack4(p[mt][0], p[mt][1], p[mt][2], p[mt][3]);
        }

        // ---- rescale O (rows q = g*4+r in PV layout) ----
        float scr[4];
#pragma unroll
        for (int r = 0; r < 4; ++r) scr[r] = __shfl(sc, g * 4 + r);
#pragma unroll
        for (int nt = 0; nt < 4; ++nt)
#pragma unroll
            for (int r = 0; r < 4; ++r) o[nt][r] *= scr[r];

        // ensure all lanes' P writes landed before cross-lane reads
        asm volatile("s_waitcnt lgkmcnt(0)" ::: "memory");

        // ---- PV: mfma(P, V) -> O[q=g*4+r][d=qr+16*nt] ----
        short8 pf0 = *reinterpret_cast<const short8*>(&Plds[wid][qr][g * 8]);
        short8 pf1 = *reinterpret_cast<const short8*>(&Plds[wid][qr][g * 8 + 32]);
#pragma unroll
        for (int nt = 0; nt < 4; ++nt) {
            short8 vf0 = *reinterpret_cast<const short8*>(&Vt[qr + 16 * nt][g * 8]);
            short8 vf1 = *reinterpret_cast<const short8*>(&Vt[qr + 16 * nt][g * 8 + 32]);
            o[nt] = __builtin_amdgcn_mfma_f32_16x16x32_bf16(pf0, vf0, o[nt], 0, 0, 0);
            o[nt] = __builtin_amdgcn_mfma_f32_16x16x32_bf16(pf1, vf1, o[nt], 0, 0, 0);
        }
        __syncthreads();   // before next iteration overwrites K/Vt
    }

    // ---- epilogue: divide by softmax denom, store fp32 ----
    const float inv = 1.0f / lrun;
    float invr[4];
#pragma unroll
    for (int r = 0; r < 4; ++r) invr[r] = __shfl(inv, g * 4 + r);

    float* op = out + ((b * SEQ + qbase) * DM + h * HD + qr);
#pragma unroll
    for (int nt = 0; nt < 4; ++nt)
#pragma unroll
        for (int r = 0; r < 4; ++r)
            op[(g * 4 + r) * DM + nt * 16] = o[nt][r] * invr[r];
}

extern "C" void kernel_launch(void* const* d_in, const int* in_sizes, int n_in,
                              void* d_out, int out_size, void* d_ws, size_t ws_size,
                              hipStream_t stream) {
    const float* q    = (const float*)d_in[0];
    const float* k    = (const float*)d_in[1];
    const float* v    = (const float*)d_in[2];
    const float* bias = (const float*)d_in[3];
    float* out        = (float*)d_out;
    attn_fwd<<<dim3(8 * 8 * 16), dim3(256), 0, stream>>>(q, k, v, bias, out);
}

// Round 2
// 161.494 us; speedup vs baseline: 1.1116x; 1.1116x over previous
//
#include <hip/hip_runtime.h>
#include <hip/hip_bf16.h>
#include <math.h>

// Attention_1322849927553: B=8, S=1024, D=512, H=8, hd=64, additive pos bias.
// Round 2: bf16 pre-pass (K tile-major swizzled, V^T tile-major swizzled) into ws,
// attn kernel with global_load_lds double-buffered staging, 32 q-rows/wave,
// exp2-domain online softmax. Round-1 kernel kept as ws_size fallback.

typedef __attribute__((ext_vector_type(8))) short short8;
typedef __attribute__((ext_vector_type(4))) float f32x4;
typedef __attribute__((ext_vector_type(4))) unsigned short u16x4;

#define SEQ   1024
#define DM    512
#define HD    64
#define NH    8
#define LOG2E 1.4426950408889634f
#define QSCALE (0.125f * LOG2E)

__device__ __forceinline__ unsigned short f2bf(float f) {
    unsigned u = __float_as_uint(f);
    u += 0x7fffu + ((u >> 16) & 1u);   // RNE
    return (unsigned short)(u >> 16);
}
__device__ __forceinline__ u16x4 pack4(float a, float b, float c, float d) {
    u16x4 r; r[0] = f2bf(a); r[1] = f2bf(b); r[2] = f2bf(c); r[3] = f2bf(d);
    return r;
}
__device__ __forceinline__ short8 pack8(const float* x) {
    short8 r;
#pragma unroll
    for (int i = 0; i < 8; ++i) r[i] = (short)f2bf(x[i]);
    return r;
}
__device__ __forceinline__ float fexp2(float x) {
#if __has_builtin(__builtin_amdgcn_exp2f)
    return __builtin_amdgcn_exp2f(x);
#else
    return exp2f(x);
#endif
}
__device__ __forceinline__ void gll16(const void* g, void* l) {
    __builtin_amdgcn_global_load_lds(
        (const __attribute__((address_space(1))) unsigned*)g,
        (__attribute__((address_space(3))) unsigned*)l, 16, 0, 0);
}

// ---------------- prep: K -> bf16, tile-major [bh][st][64s][64d], chunk^=(s&7) ----------------
__global__ __launch_bounds__(256)
void prep_k(const float* __restrict__ k, short* __restrict__ kws) {
    int tid = blockIdx.x * 256 + threadIdx.x;      // 524288 = 8*1024*8*8
    int d8 = tid & 7, h = (tid >> 3) & 7, s = (tid >> 6) & 1023, b = tid >> 16;
    const float* src = k + ((size_t)(b * SEQ + s) * DM + h * HD + d8 * 8);
    float4 x0 = *(const float4*)src, x1 = *(const float4*)(src + 4);
    float xs[8] = {x0.x, x0.y, x0.z, x0.w, x1.x, x1.y, x1.z, x1.w};
    int bh = b * NH + h;
    size_t idx = (size_t)(bh * 16 + (s >> 6)) * 4096 + (s & 63) * 64 + ((d8 ^ (s & 7)) * 8);
    *(short8*)(kws + idx) = pack8(xs);
}

// ---------------- prep: V -> bf16 transposed, tile-major [bh][st][64d][64s], chunk^=(d&7) ----
__global__ __launch_bounds__(256)
void prep_v(const float* __restrict__ v, short* __restrict__ vtws) {
    __shared__ short Vs[64][72];
    int bid = blockIdx.x;                // 1024 = 8*8*16
    int st = bid & 15, h = (bid >> 4) & 7, b = bid >> 7;
    int t = threadIdx.x;
    {
        int sl = t >> 2, dc = t & 3;
        const float* src = v + ((size_t)(b * SEQ + st * 64 + sl) * DM + h * HD + dc * 16);
        float4 a0 = ((const float4*)src)[0], a1 = ((const float4*)src)[1],
               a2 = ((const float4*)src)[2], a3 = ((const float4*)src)[3];
        float xs0[8] = {a0.x, a0.y, a0.z, a0.w, a1.x, a1.y, a1.z, a1.w};
        float xs1[8] = {a2.x, a2.y, a2.z, a2.w, a3.x, a3.y, a3.z, a3.w};
        *(short8*)&Vs[sl][dc * 16]     = pack8(xs0);
        *(short8*)&Vs[sl][dc * 16 + 8] = pack8(xs1);
    }
    __syncthreads();
    {
        int d = t >> 2, sc = t & 3;
        short vals[16];
#pragma unroll
        for (int j = 0; j < 16; ++j) vals[j] = Vs[sc * 16 + j][d];
        short8 w0, w1;
#pragma unroll
        for (int j = 0; j < 8; ++j) { w0[j] = vals[j]; w1[j] = vals[8 + j]; }
        int bh = b * NH + h;
        size_t base = (size_t)(bh * 16 + st) * 4096 + d * 64;
        int c0 = (sc * 2) ^ (d & 7), c1 = (sc * 2 + 1) ^ (d & 7);
        *(short8*)(vtws + base + c0 * 8) = w0;
        *(short8*)(vtws + base + c1 * 8) = w1;
    }
}

// ---------------- fused attention, v2 ----------------
__global__ __launch_bounds__(256, 2)
void attn_fwd2(const float* __restrict__ q, const float* __restrict__ bias,
               const short* __restrict__ kws, const short* __restrict__ vtws,
               float* __restrict__ out)
{
    __shared__ short Ksh[2][4096];     // [64 s][64 d] bf16, chunk^=(s&7)
    __shared__ short Vsh[2][4096];     // [64 d][64 s] bf16, chunk^=(d&7)
    __shared__ short Plds[4][32][72];  // per-wave P [q][k], +pad

    const int t = threadIdx.x;
    const int wid = t >> 6, lane = t & 63;
    const int qr = lane & 15, g = lane >> 4;

    int idx = blockIdx.x;
    const int b = idx & 7;  idx >>= 3;
    const int h = idx & 7;
    const int qt = idx >> 3;                 // 0..7, stride-64 blocks -> same XCD per (b,h)
    const int qbw = qt * 128 + wid * 32;
    const int bh = b * NH + h;

    // ---- Q fragments (B operand), scale*log2e folded ----
    short8 qf[2][2];
#pragma unroll
    for (int sub = 0; sub < 2; ++sub) {
        const float* qp = q + ((size_t)(b * SEQ + qbw + sub * 16 + qr) * DM + h * HD);
#pragma unroll
        for (int c = 0; c < 2; ++c) {
            float4 x0 = *(const float4*)(qp + g * 8 + 32 * c);
            float4 x1 = *(const float4*)(qp + g * 8 + 32 * c + 4);
            float xs[8] = {x0.x * QSCALE, x0.y * QSCALE, x0.z * QSCALE, x0.w * QSCALE,
                           x1.x * QSCALE, x1.y * QSCALE, x1.z * QSCALE, x1.w * QSCALE};
            qf[sub][c] = pack8(xs);
        }
    }

    f32x4 o[2][4];
#pragma unroll
    for (int sub = 0; sub < 2; ++sub)
#pragma unroll
        for (int nt = 0; nt < 4; ++nt) o[sub][nt] = (f32x4){0.f, 0.f, 0.f, 0.f};
    float m0 = -INFINITY, m1 = -INFINITY, l0 = 0.f, l1 = 0.f;

    const size_t tb0 = (size_t)bh * 16 * 4096;   // shorts
    // ---- prologue: stage tile 0 ----
    {
        const short* gk = kws + tb0 + wid * 512 + lane * 8;
        const short* gv = vtws + tb0 + wid * 512 + lane * 8;
        gll16(gk,        &Ksh[0][wid * 512]);
        gll16(gk + 2048, &Ksh[0][2048 + wid * 512]);
        gll16(gv,        &Vsh[0][wid * 512]);
        gll16(gv + 2048, &Vsh[0][2048 + wid * 512]);
    }
    __syncthreads();

    int cur = 0;
    for (int kt = 0; kt < 16; ++kt) {
        // ---- stage next tile into other buffer (loads fly during compute) ----
        if (kt < 15) {
            const size_t tb = tb0 + (size_t)(kt + 1) * 4096;
            const short* gk = kws + tb + wid * 512 + lane * 8;
            const short* gv = vtws + tb + wid * 512 + lane * 8;
            int nxt = cur ^ 1;
            gll16(gk,        &Ksh[nxt][wid * 512]);
            gll16(gk + 2048, &Ksh[nxt][2048 + wid * 512]);
            gll16(gv,        &Vsh[nxt][wid * 512]);
            gll16(gv + 2048, &Vsh[nxt][2048 + wid * 512]);
        }

        // ---- bias loads (fp32, L2/L3-resident) ----
        float4 bv[2][4];
#pragma unroll
        for (int sub = 0; sub < 2; ++sub) {
            const float* bp = bias + ((size_t)(h * SEQ + qbw + sub * 16 + qr) * SEQ + kt * 64 + g * 4);
#pragma unroll
            for (int mt = 0; mt < 4; ++mt) bv[sub][mt] = *(const float4*)(bp + 16 * mt);
        }

        // ---- QK^T: S^T = mfma(K, Q); lane holds S[q=qr][k=16mt+4g+r] (x2 subs) ----
        f32x4 acc[2][4];
#pragma unroll
        for (int sub = 0; sub < 2; ++sub)
#pragma unroll
            for (int mt = 0; mt < 4; ++mt) acc[sub][mt] = (f32x4){0.f, 0.f, 0.f, 0.f};
        __builtin_amdgcn_s_setprio(1);
#pragma unroll
        for (int mt = 0; mt < 4; ++mt) {
#pragma unroll
            for (int c = 0; c < 2; ++c) {
                const short8 kf = *(const short8*)
                    &Ksh[cur][(qr + 16 * mt) * 64 + ((g + 4 * c) ^ (qr & 7)) * 8];
                acc[0][mt] = __builtin_amdgcn_mfma_f32_16x16x32_bf16(kf, qf[0][c], acc[0][mt], 0, 0, 0);
                acc[1][mt] = __builtin_amdgcn_mfma_f32_16x16x32_bf16(kf, qf[1][c], acc[1][mt], 0, 0, 0);
            }
        }
        __builtin_amdgcn_s_setprio(0);

        // ---- online softmax in exp2 domain (bias folded via fma) ----
        float sc[2];
#pragma unroll
        for (int sub = 0; sub < 2; ++sub) {
            float s[4][4];
            float tmax = -INFINITY;
#pragma unroll
            for (int mt = 0; mt < 4; ++mt)
#pragma unroll
                for (int r = 0; r < 4; ++r) {
                    float val = fmaf(((const float*)&bv[sub][mt])[r], LOG2E, acc[sub][mt][r]);
                    s[mt][r] = val;
                    tmax = fmaxf(tmax, val);
                }
            tmax = fmaxf(tmax, __shfl_xor(tmax, 16));
            tmax = fmaxf(tmax, __shfl_xor(tmax, 32));
            const float mold = (sub == 0) ? m0 : m1;
            const float mnew = fmaxf(mold, tmax);
            float ssum = 0.f;
#pragma unroll
            for (int mt = 0; mt < 4; ++mt) {
                float e0 = fexp2(s[mt][0] - mnew);
                float e1 = fexp2(s[mt][1] - mnew);
                float e2 = fexp2(s[mt][2] - mnew);
                float e3 = fexp2(s[mt][3] - mnew);
                ssum += (e0 + e1) + (e2 + e3);
                *(u16x4*)&Plds[wid][sub * 16 + qr][16 * mt + g * 4] = pack4(e0, e1, e2, e3);
            }
            ssum += __shfl_xor(ssum, 16);
            ssum += __shfl_xor(ssum, 32);
            const float scs = fexp2(mold - mnew);   // first iter: exp2(-inf)=0
            if (sub == 0) { l0 = l0 * scs + ssum; m0 = mnew; }
            else          { l1 = l1 * scs + ssum; m1 = mnew; }
            sc[sub] = scs;
        }

        // ---- rescale O (rows q = 4g+r in PV layout) ----
#pragma unroll
        for (int sub = 0; sub < 2; ++sub) {
            float scr[4];
#pragma unroll
            for (int r = 0; r < 4; ++r) scr[r] = __shfl(sc[sub], g * 4 + r);
#pragma unroll
            for (int nt = 0; nt < 4; ++nt)
#pragma unroll
                for (int r = 0; r < 4; ++r) o[sub][nt][r] *= scr[r];
        }

        // P writes (cross-lane within wave) must land before PV reads
        asm volatile("s_waitcnt lgkmcnt(0)" ::: "memory");
        __builtin_amdgcn_sched_barrier(0);

        // ---- PV: O += mfma(P, V^T-frag) ----
        __builtin_amdgcn_s_setprio(1);
#pragma unroll
        for (int c = 0; c < 2; ++c) {
            short8 pf0 = *(const short8*)&Plds[wid][qr][g * 8 + 32 * c];
            short8 pf1 = *(const short8*)&Plds[wid][16 + qr][g * 8 + 32 * c];
#pragma unroll
            for (int nt = 0; nt < 4; ++nt) {
                short8 vf = *(const short8*)
                    &Vsh[cur][(qr + 16 * nt) * 64 + ((g + 4 * c) ^ (qr & 7)) * 8];
                o[0][nt] = __builtin_amdgcn_mfma_f32_16x16x32_bf16(pf0, vf, o[0][nt], 0, 0, 0);
                o[1][nt] = __builtin_amdgcn_mfma_f32_16x16x32_bf16(pf1, vf, o[1][nt], 0, 0, 0);
            }
        }
        __builtin_amdgcn_s_setprio(0);

        __syncthreads();   // drains vmcnt (next tile staged) + protects buffers
        cur ^= 1;
    }

    // ---- epilogue ----
    const float inv0 = 1.0f / l0, inv1 = 1.0f / l1;
#pragma unroll
    for (int sub = 0; sub < 2; ++sub) {
        const float invv = sub ? inv1 : inv0;
        float invr[4];
#pragma unroll
        for (int r = 0; r < 4; ++r) invr[r] = __shfl(invv, g * 4 + r);
        float* op = out + ((size_t)(b * SEQ + qbw + sub * 16) * DM + h * HD + qr);
#pragma unroll
        for (int nt = 0; nt < 4; ++nt)
#pragma unroll
            for (int r = 0; r < 4; ++r)
                op[(size_t)(g * 4 + r) * DM + nt * 16] = o[sub][nt][r] * invr[r];
    }
}

// ---------------- round-1 kernel kept as ws_size fallback ----------------
__global__ __launch_bounds__(256, 3)
void attn_fwd(const float* __restrict__ q, const float* __restrict__ k,
              const float* __restrict__ v, const float* __restrict__ bias,
              float* __restrict__ out)
{
    __shared__ short Klds[64][72];
    __shared__ short Vt[64][72];
    __shared__ short Pl[4][16][72];

    const int t = threadIdx.x;
    const int wid = t >> 6;
    const int lane = t & 63;
    const int qr = lane & 15;
    const int g = lane >> 4;

    int idx = blockIdx.x;
    const int b = idx & 7;  idx >>= 3;
    const int h = idx & 7;
    const int qtile = idx >> 3;
    const int qbase = qtile * 64 + wid * 16;

    const float* qp = q + ((b * SEQ + qbase + qr) * DM + h * HD);
    short8 qf[2];
#pragma unroll
    for (int c = 0; c < 2; ++c) {
        float4 x0 = *reinterpret_cast<const float4*>(qp + g * 8 + 32 * c);
        float4 x1 = *reinterpret_cast<const float4*>(qp + g * 8 + 32 * c + 4);
        float xs[8] = {x0.x * 0.125f, x0.y * 0.125f, x0.z * 0.125f, x0.w * 0.125f,
                       x1.x * 0.125f, x1.y * 0.125f, x1.z * 0.125f, x1.w * 0.125f};
        qf[c] = pack8(xs);
    }

    f32x4 o[4];
#pragma unroll
    for (int nt = 0; nt < 4; ++nt) o[nt] = (f32x4){0.f, 0.f, 0.f, 0.f};
    float mrun = -INFINITY, lrun = 0.f;

    const int jrow = t & 63;
    const int cc = t >> 6;

    for (int kt = 0; kt < 16; ++kt) {
        const int kbase = kt * 64;
        {
            const float4* kp4 = reinterpret_cast<const float4*>(
                k + ((b * SEQ + kbase + jrow) * DM + h * HD + cc * 16));
            float4 a0 = kp4[0], a1 = kp4[1], a2 = kp4[2], a3 = kp4[3];
            u16x4* dst = reinterpret_cast<u16x4*>(&Klds[jrow][cc * 16]);
            dst[0] = pack4(a0.x, a0.y, a0.z, a0.w);
            dst[1] = pack4(a1.x, a1.y, a1.z, a1.w);
            dst[2] = pack4(a2.x, a2.y, a2.z, a2.w);
            dst[3] = pack4(a3.x, a3.y, a3.z, a3.w);
        }
        {
            const float* vp = v + ((b * SEQ + kbase + cc * 16) * DM + h * HD + jrow);
            float vv[16];
#pragma unroll
            for (int jj = 0; jj < 16; ++jj) vv[jj] = vp[jj * DM];
            u16x4* dst = reinterpret_cast<u16x4*>(&Vt[jrow][cc * 16]);
            dst[0] = pack4(vv[0], vv[1], vv[2], vv[3]);
            dst[1] = pack4(vv[4], vv[5], vv[6], vv[7]);
            dst[2] = pack4(vv[8], vv[9], vv[10], vv[11]);
            dst[3] = pack4(vv[12], vv[13], vv[14], vv[15]);
        }
        __syncthreads();

        const float* bp = bias + ((h * SEQ + qbase + qr) * SEQ + kbase + g * 4);
        float4 bv0 = *reinterpret_cast<const float4*>(bp);
        float4 bv1 = *reinterpret_cast<const float4*>(bp + 16);
        float4 bv2 = *reinterpret_cast<const float4*>(bp + 32);
        float4 bv3 = *reinterpret_cast<const float4*>(bp + 48);

        f32x4 acc[4];
#pragma unroll
        for (int mt = 0; mt < 4; ++mt) {
            f32x4 a = (f32x4){0.f, 0.f, 0.f, 0.f};
#pragma unroll
            for (int c = 0; c < 2; ++c) {
                short8 kf = *reinterpret_cast<const short8*>(
                    &Klds[qr + 16 * mt][g * 8 + 32 * c]);
                a = __builtin_amdgcn_mfma_f32_16x16x32_bf16(kf, qf[c], a, 0, 0, 0);
            }
            acc[mt] = a;
        }
        acc[0][0] += bv0.x; acc[0][1] += bv0.y; acc[0][2] += bv0.z; acc[0][3] += bv0.w;
        acc[1][0] += bv1.x; acc[1][1] += bv1.y; acc[1][2] += bv1.z; acc[1][3] += bv1.w;
        acc[2][0] += bv2.x; acc[2][1] += bv2.y; acc[2][2] += bv2.z; acc[2][3] += bv2.w;
        acc[3][0] += bv3.x; acc[3][1] += bv3.y; acc[3][2] += bv3.z; acc[3][3] += bv3.w;

        float tmax = acc[0][0];
#pragma unroll
        for (int mt = 0; mt < 4; ++mt)
#pragma unroll
            for (int r = 0; r < 4; ++r) tmax = fmaxf(tmax, acc[mt][r]);
        tmax = fmaxf(tmax, __shfl_xor(tmax, 16));
        tmax = fmaxf(tmax, __shfl_xor(tmax, 32));
        const float mnew = fmaxf(mrun, tmax);

        float p[4][4];
        float ssum = 0.f;
#pragma unroll
        for (int mt = 0; mt < 4; ++mt)
#pragma unroll
            for (int r = 0; r < 4; ++r) {
                float e = __expf(acc[mt][r] - mnew);
                p[mt][r] = e;
                ssum += e;
            }
        ssum += __shfl_xor(ssum, 16);
        ssum += __shfl_xor(ssum, 32);
        const float scv = __expf(mrun - mnew);
        lrun = lrun * scv + ssum;
        mrun = mnew;

#pragma unroll
        for (int mt = 0; mt < 4; ++mt) {
            *reinterpret_cast<u16x4*>(&Pl[wid][qr][16 * mt + g * 4]) =
                pack4(p[mt][0], p[mt][1], p[mt][2], p[mt][3]);
        }

        float scr[4];
#pragma unroll
        for (int r = 0; r < 4; ++r) scr[r] = __shfl(scv, g * 4 + r);
#pragma unroll
        for (int nt = 0; nt < 4; ++nt)
#pragma unroll
            for (int r = 0; r < 4; ++r) o[nt][r] *= scr[r];

        asm volatile("s_waitcnt lgkmcnt(0)" ::: "memory");
        __builtin_amdgcn_sched_barrier(0);

        short8 pf0 = *reinterpret_cast<const short8*>(&Pl[wid][qr][g * 8]);
        short8 pf1 = *reinterpret_cast<const short8*>(&Pl[wid][qr][g * 8 + 32]);
#pragma unroll
        for (int nt = 0; nt < 4; ++nt) {
            short8 vf0 = *reinterpret_cast<const short8*>(&Vt[qr + 16 * nt][g * 8]);
            short8 vf1 = *reinterpret_cast<const short8*>(&Vt[qr + 16 * nt][g * 8 + 32]);
            o[nt] = __builtin_amdgcn_mfma_f32_16x16x32_bf16(pf0, vf0, o[nt], 0, 0, 0);
            o[nt] = __builtin_amdgcn_mfma_f32_16x16x32_bf16(pf1, vf1, o[nt], 0, 0, 0);
        }
        __syncthreads();
    }

    const float inv = 1.0f / lrun;
    float invr[4];
#pragma unroll
    for (int r = 0; r < 4; ++r) invr[r] = __shfl(inv, g * 4 + r);

    float* op = out + ((b * SEQ + qbase) * DM + h * HD + qr);
#pragma unroll
    for (int nt = 0; nt < 4; ++nt)
#pragma unroll
        for (int r = 0; r < 4; ++r)
            op[(g * 4 + r) * DM + nt * 16] = o[nt][r] * invr[r];
}

extern "C" void kernel_launch(void* const* d_in, const int* in_sizes, int n_in,
                              void* d_out, int out_size, void* d_ws, size_t ws_size,
                              hipStream_t stream) {
    const float* q    = (const float*)d_in[0];
    const float* k    = (const float*)d_in[1];
    const float* v    = (const float*)d_in[2];
    const float* bias = (const float*)d_in[3];
    float* out        = (float*)d_out;

    const size_t elems = (size_t)8 * NH * SEQ * HD;          // 4,194,304 shorts each
    const size_t need  = 2 * elems * sizeof(short);          // 16,777,216 B
    if (ws_size >= need) {
        short* kws  = (short*)d_ws;
        short* vtws = kws + elems;
        prep_k<<<dim3(2048), dim3(256), 0, stream>>>(k, kws);
        prep_v<<<dim3(1024), dim3(256), 0, stream>>>(v, vtws);
        attn_fwd2<<<dim3(512), dim3(256), 0, stream>>>(q, bias, kws, vtws, out);
    } else {
        attn_fwd<<<dim3(1024), dim3(256), 0, stream>>>(q, k, v, bias, out);
    }
}